// Round 2
// baseline (76.445 us; speedup 1.0000x reference)
//
#include <hip/hip_runtime.h>
#include <hip/hip_bf16.h>

#define QLEN   1024
#define MLEN   1024
#define KLEN   2048
#define BATCH  8
#define DMODEL 1024
#define NCOLS  (BATCH * DMODEL)   // 8192
#define FTLEN  1025

#define BM 128
#define BN 256
#define BK 64
#define NT 18   // band: K in [m0, m0+1152), 18 tiles of 64

typedef __attribute__((ext_vector_type(4))) float f32x4;
typedef __attribute__((ext_vector_type(8))) short bf16x8;

typedef __attribute__((address_space(1))) const unsigned int as1_u32;
typedef __attribute__((address_space(3))) unsigned int as3_u32;

static __device__ __forceinline__ unsigned short f2bf(float f) {
    unsigned int u = __builtin_bit_cast(unsigned int, f);
    return (unsigned short)((u + 0x7fffu + ((u >> 16) & 1u)) >> 16);
}
static __device__ __forceinline__ float bf2f(unsigned short s) {
    return __builtin_bit_cast(float, (unsigned int)s << 16);
}

// ---------------------------------------------------------------------------
// Kernel 1: cat = concat(mems, dec) (+ pos_emb), cast bf16, store TRANSPOSED:
// catT[n][k], n = b*1024 + d (8192 rows), k = l (2048 cols, contiguous).
// ---------------------------------------------------------------------------
__global__ __launch_bounds__(256) void prep_transpose(
    const float* __restrict__ dec, const float* __restrict__ pos,
    const float* __restrict__ mems, const int* __restrict__ addp,
    unsigned short* __restrict__ catT)
{
    __shared__ unsigned short T[64][72];
    const int lt = blockIdx.x, dt = blockIdx.y, b = blockIdx.z;
    const int tid = threadIdx.x;
    const int add_position = addp[0];
    const int l0 = lt * 64, d0 = dt * 64;

    const int lrow = tid >> 4;         // 0..15
    const int dcol = (tid & 15) * 4;   // 0..60
    for (int p = 0; p < 4; ++p) {
        const int ll = p * 16 + lrow;
        const int l = l0 + ll;
        const int d = d0 + dcol;
        const float* src = (l < MLEN)
            ? (mems + (size_t)l * NCOLS + b * DMODEL + d)
            : (dec + (size_t)(l - MLEN) * NCOLS + b * DMODEL + d);
        float4 v = *reinterpret_cast<const float4*>(src);
        if (add_position) {
            float4 pv = *reinterpret_cast<const float4*>(pos + (size_t)l * DMODEL + d);
            v.x += pv.x; v.y += pv.y; v.z += pv.z; v.w += pv.w;
        }
        T[dcol + 0][ll] = f2bf(v.x);
        T[dcol + 1][ll] = f2bf(v.y);
        T[dcol + 2][ll] = f2bf(v.z);
        T[dcol + 3][ll] = f2bf(v.w);
    }
    __syncthreads();
    for (int p = 0; p < 2; ++p) {
        const int idx = p * 256 + tid;
        const int r = idx >> 3;
        const int c = (idx & 7) * 8;
        int4 v = *reinterpret_cast<const int4*>(&T[r][c]);
        size_t n = (size_t)(b * DMODEL + d0 + r);
        *reinterpret_cast<int4*>(&catT[n * KLEN + l0 + c]) = v;
    }
}

// ---------------------------------------------------------------------------
// Kernel 2: W[m][k] bf16, W[m][m+t] = cos(2*pi*(m*t mod 1025)/1025)/sqrt(1025)
// ---------------------------------------------------------------------------
__global__ __launch_bounds__(256) void fill_w(unsigned short* __restrict__ W)
{
    const int idx = blockIdx.x * 256 + threadIdx.x;
    const int m = idx >> 9;
    const int k4 = (idx & 511) * 4;
    union { unsigned short s[4]; int2 v; } u;
    for (int j = 0; j < 4; ++j) {
        const int k = k4 + j;
        const int t = k - m;
        float w = 0.0f;
        if (t >= 0 && t < FTLEN) {
            const int r = (m * t) % FTLEN;
            const float theta = (6.283185307179586f / (float)FTLEN) * (float)r;
            w = cosf(theta) * 0.03123475237772121f;
        }
        u.s[j] = f2bf(w);
    }
    *reinterpret_cast<int2*>(&W[(size_t)m * KLEN + k4]) = u.v;
}

// ---------------------------------------------------------------------------
// Kernel 3: banded GEMM, BM=128 x BN=256, 8 waves, triple-buffered LDS,
// counted-vmcnt pipeline (2 K-steps in flight), raw s_barrier.
// x[m][n] = bf16( dec[m][n] + (1/sqrt(2048)) * sum_k W[m][k]*catT[n][k] )
// ---------------------------------------------------------------------------
__global__ __launch_bounds__(512) void gemm_band2(
    const unsigned short* __restrict__ W,     // [1024][2048]
    const unsigned short* __restrict__ catT,  // [8192][2048]
    const float* __restrict__ dec,            // [1024][8192]
    unsigned short* __restrict__ xout)        // bf16 [1024][8192]
{
    __shared__ unsigned short Alds[3][BM * BK];   // 3 x 16KB
    __shared__ unsigned short Blds[3][BN * BK];   // 3 x 32KB  (total 144KB)

    const int tid = threadIdx.x;
    const int wave = tid >> 6, lane = tid & 63;

    // XCD-chunked swizzle: xcd = bid&7 gets n_idx in [xcd*4, xcd*4+4), all 8 m.
    const int bid = blockIdx.x;
    const int xcd = bid & 7;
    const int kk = bid >> 3;              // 0..31
    const int m_idx = kk >> 2;            // 0..7
    const int n_idx = xcd * 4 + (kk & 3); // 0..31
    const int m0 = m_idx * BM, n0 = n_idx * BN;
    const int wm = wave >> 2, wn = wave & 3;   // 2 x 4 wave grid

    f32x4 acc[4][4];
    for (int i = 0; i < 4; ++i)
        for (int j = 0; j < 4; ++j)
            acc[i][j] = (f32x4){0.f, 0.f, 0.f, 0.f};

    const int srow = tid >> 3;           // 0..63
    const int scol = (tid & 7) * 8;      // element col (16B chunks)
    const int fr = lane & 15;
    const int kg = lane >> 4;

#define STAGE(S, T) do {                                                        \
    const int k0_ = m0 + (T) * BK;                                              \
    _Pragma("unroll")                                                           \
    for (int p = 0; p < 2; ++p) {                                               \
        const int row = p * 64 + srow;                                          \
        __builtin_amdgcn_global_load_lds(                                       \
            (as1_u32*)(const void*)(W + (size_t)(m0 + row) * KLEN + k0_ + scol),\
            (as3_u32*)(void*)(&Alds[S][row * BK + scol]), 16, 0, 0);            \
    }                                                                           \
    _Pragma("unroll")                                                           \
    for (int p = 0; p < 4; ++p) {                                               \
        const int row = p * 64 + srow;                                          \
        __builtin_amdgcn_global_load_lds(                                       \
            (as1_u32*)(const void*)(catT + (size_t)(n0 + row) * KLEN + k0_ + scol),\
            (as3_u32*)(void*)(&Blds[S][row * BK + scol]), 16, 0, 0);            \
    }                                                                           \
} while (0)

    STAGE(0, 0);
    STAGE(1, 1);

    for (int t = 0; t < NT; ++t) {
        // retire batch t (6 oldest loads); keep t+1 (and soon t+2) in flight
        if (t == NT - 1)
            asm volatile("s_waitcnt vmcnt(0)\ns_barrier" ::: "memory");
        else
            asm volatile("s_waitcnt vmcnt(6)\ns_barrier" ::: "memory");

        if (t + 2 < NT) {
            const int s = (t + 2) % 3;
            STAGE(s, t + 2);
        }

        const unsigned short* Ab = Alds[t % 3];
        const unsigned short* Bb = Blds[t % 3];
#pragma unroll
        for (int ks = 0; ks < 2; ++ks) {
            bf16x8 a[4], b[4];
#pragma unroll
            for (int f = 0; f < 4; ++f)
                a[f] = *reinterpret_cast<const bf16x8*>(
                    Ab + (wm * 64 + f * 16 + fr) * BK + ks * 32 + kg * 8);
#pragma unroll
            for (int f = 0; f < 4; ++f)
                b[f] = *reinterpret_cast<const bf16x8*>(
                    Bb + (wn * 64 + f * 16 + fr) * BK + ks * 32 + kg * 8);
#pragma unroll
            for (int fm = 0; fm < 4; ++fm)
#pragma unroll
                for (int fn = 0; fn < 4; ++fn)
                    acc[fm][fn] = __builtin_amdgcn_mfma_f32_16x16x32_bf16(
                        a[fm], b[fn], acc[fm][fn], 0, 0, 0);
        }
    }
#undef STAGE

    // epilogue: x = bf16(dec + acc/sqrt(2048)); C/D: col=lane&15, row=(lane>>4)*4+j
    const float inv = 0.022097086912079612f;  // 1/sqrt(2048)
    const int col16 = lane & 15, rquad = lane >> 4;
#pragma unroll
    for (int fm = 0; fm < 4; ++fm)
#pragma unroll
        for (int fn = 0; fn < 4; ++fn)
#pragma unroll
            for (int j = 0; j < 4; ++j) {
                const int m = m0 + wm * 64 + fm * 16 + rquad * 4 + j;
                const int n = n0 + wn * 64 + fn * 16 + col16;
                const size_t o = (size_t)m * NCOLS + n;
                xout[o] = f2bf(dec[o] + acc[fm][fn][j] * inv);
            }
}

// ---------------------------------------------------------------------------
// Kernel 4: LayerNorm over d=1024 per (m,b) row, bf16 input, f32 output.
// x rows are contiguous: offset = row*1024 + d  (row = m*8+b).
// ---------------------------------------------------------------------------
__global__ __launch_bounds__(256) void layernorm_rows(
    const unsigned short* __restrict__ x, const float* __restrict__ gamma,
    const float* __restrict__ beta, float* __restrict__ out)
{
    __shared__ float ps[4], pq[4];
    const int row = blockIdx.x;
    const int tid = threadIdx.x;
    ushort4 u = *reinterpret_cast<const ushort4*>(x + (size_t)row * DMODEL + tid * 4);
    float vx = bf2f(u.x), vy = bf2f(u.y), vz = bf2f(u.z), vw = bf2f(u.w);
    float s  = vx + vy + vz + vw;
    float sq = vx * vx + vy * vy + vz * vz + vw * vw;
    for (int off = 32; off > 0; off >>= 1) {
        s  += __shfl_down(s, off);
        sq += __shfl_down(sq, off);
    }
    const int wave = tid >> 6, lane = tid & 63;
    if (lane == 0) { ps[wave] = s; pq[wave] = sq; }
    __syncthreads();
    if (tid == 0) {
        float ts = ps[0] + ps[1] + ps[2] + ps[3];
        float tq = pq[0] + pq[1] + pq[2] + pq[3];
        float mu = ts * (1.0f / DMODEL);
        float var = tq * (1.0f / DMODEL) - mu * mu;
        ps[0] = mu;
        pq[0] = rsqrtf(var + 1e-5f);
    }
    __syncthreads();
    const float mu = ps[0], rs = pq[0];
    float4 g  = *reinterpret_cast<const float4*>(gamma + tid * 4);
    float4 be = *reinterpret_cast<const float4*>(beta + tid * 4);
    float4 o;
    o.x = g.x * (vx - mu) * rs + be.x;
    o.y = g.y * (vy - mu) * rs + be.y;
    o.z = g.z * (vz - mu) * rs + be.z;
    o.w = g.w * (vw - mu) * rs + be.w;
    *reinterpret_cast<float4*>(out + (size_t)row * DMODEL + tid * 4) = o;
}

extern "C" void kernel_launch(void* const* d_in, const int* in_sizes, int n_in,
                              void* d_out, int out_size, void* d_ws, size_t ws_size,
                              hipStream_t stream)
{
    const float* dec   = (const float*)d_in[0];
    const float* pos   = (const float*)d_in[1];
    const float* mems  = (const float*)d_in[2];
    const float* gamma = (const float*)d_in[3];
    const float* beta  = (const float*)d_in[4];
    const int*   addp  = (const int*)d_in[5];
    float* out = (float*)d_out;

    // ws: catT bf16 [8192][2048] (32MB) | W bf16 [1024][2048] (4MB) | x bf16 (16MB)
    unsigned short* catT = (unsigned short*)d_ws;
    unsigned short* Wmat = catT + (size_t)NCOLS * KLEN;
    unsigned short* x    = Wmat + (size_t)QLEN * KLEN;

    prep_transpose<<<dim3(32, 16, 8), 256, 0, stream>>>(dec, pos, mems, addp, catT);
    fill_w<<<2048, 256, 0, stream>>>(Wmat);
    gemm_band2<<<256, 512, 0, stream>>>(Wmat, catT, dec, x);
    layernorm_rows<<<8192, 256, 0, stream>>>(x, gamma, beta, out);
}

// Round 3
// 69.690 us; speedup vs baseline: 1.0969x; 1.0969x over previous
//
#include <hip/hip_runtime.h>
#include <hip/hip_bf16.h>

#define QLEN   1024
#define MLEN   1024
#define KLEN   2048
#define BATCH  8
#define DMODEL 1024
#define NCOLS  (BATCH * DMODEL)   // 8192
#define FTLEN  1025

#define BM 128
#define BN 256
#define BK 64
#define NT 18   // band: K in [m0, m0+1152), 18 tiles of 64

typedef __attribute__((ext_vector_type(4))) float f32x4;
typedef __attribute__((ext_vector_type(8))) short bf16x8;

typedef __attribute__((address_space(1))) const unsigned int as1_u32;
typedef __attribute__((address_space(3))) unsigned int as3_u32;

static __device__ __forceinline__ unsigned short f2bf(float f) {
    unsigned int u = __builtin_bit_cast(unsigned int, f);
    return (unsigned short)((u + 0x7fffu + ((u >> 16) & 1u)) >> 16);
}
static __device__ __forceinline__ float bf2f(unsigned short s) {
    return __builtin_bit_cast(float, (unsigned int)s << 16);
}

// ---------------------------------------------------------------------------
// Kernel 1: cat = concat(mems, dec) (+ pos_emb), cast bf16, store TRANSPOSED:
// catT[n][k], n = b*1024 + d (8192 rows), k = l (2048 cols, contiguous).
// ---------------------------------------------------------------------------
__global__ __launch_bounds__(256) void prep_transpose(
    const float* __restrict__ dec, const float* __restrict__ pos,
    const float* __restrict__ mems, const int* __restrict__ addp,
    unsigned short* __restrict__ catT)
{
    __shared__ unsigned short T[64][72];
    const int lt = blockIdx.x, dt = blockIdx.y, b = blockIdx.z;
    const int tid = threadIdx.x;
    const int add_position = addp[0];
    const int l0 = lt * 64, d0 = dt * 64;

    const int lrow = tid >> 4;         // 0..15
    const int dcol = (tid & 15) * 4;   // 0..60
    for (int p = 0; p < 4; ++p) {
        const int ll = p * 16 + lrow;
        const int l = l0 + ll;
        const int d = d0 + dcol;
        const float* src = (l < MLEN)
            ? (mems + (size_t)l * NCOLS + b * DMODEL + d)
            : (dec + (size_t)(l - MLEN) * NCOLS + b * DMODEL + d);
        float4 v = *reinterpret_cast<const float4*>(src);
        if (add_position) {
            float4 pv = *reinterpret_cast<const float4*>(pos + (size_t)l * DMODEL + d);
            v.x += pv.x; v.y += pv.y; v.z += pv.z; v.w += pv.w;
        }
        T[dcol + 0][ll] = f2bf(v.x);
        T[dcol + 1][ll] = f2bf(v.y);
        T[dcol + 2][ll] = f2bf(v.z);
        T[dcol + 3][ll] = f2bf(v.w);
    }
    __syncthreads();
    for (int p = 0; p < 2; ++p) {
        const int idx = p * 256 + tid;
        const int r = idx >> 3;
        const int c = (idx & 7) * 8;
        int4 v = *reinterpret_cast<const int4*>(&T[r][c]);
        size_t n = (size_t)(b * DMODEL + d0 + r);
        *reinterpret_cast<int4*>(&catT[n * KLEN + l0 + c]) = v;
    }
}

// ---------------------------------------------------------------------------
// Kernel 2: W[m][k] bf16, W[m][m+t] = cos(2*pi*(m*t mod 1025)/1025)/sqrt(1025)
// ---------------------------------------------------------------------------
__global__ __launch_bounds__(256) void fill_w(unsigned short* __restrict__ W)
{
    const int idx = blockIdx.x * 256 + threadIdx.x;
    const int m = idx >> 9;
    const int k4 = (idx & 511) * 4;
    union { unsigned short s[4]; int2 v; } u;
    for (int j = 0; j < 4; ++j) {
        const int k = k4 + j;
        const int t = k - m;
        float w = 0.0f;
        if (t >= 0 && t < FTLEN) {
            const int r = (m * t) % FTLEN;
            const float theta = (6.283185307179586f / (float)FTLEN) * (float)r;
            w = cosf(theta) * 0.03123475237772121f;
        }
        u.s[j] = f2bf(w);
    }
    *reinterpret_cast<int2*>(&W[(size_t)m * KLEN + k4]) = u.v;
}

// ---------------------------------------------------------------------------
// Kernel 3: banded GEMM, BM=128 x BN=256, 8 waves, triple-buffered LDS,
// counted-vmcnt pipeline (2 K-steps in flight), raw s_barrier.
// T2 XOR-swizzle (both sides, rule #21): LDS physical stays linear for
// global_load_lds; the GLOBAL source column is pre-swizzled so that
// logical elem (row, c) lives at LDS elem  row*64 + (c ^ 8*(row&7)).
// Fragment reads apply the same XOR. Kills the 16-way b128 conflict.
// Output: ft[m][n] bf16 (dec-add moved to LN).
// ---------------------------------------------------------------------------
__global__ __launch_bounds__(512) void gemm_band3(
    const unsigned short* __restrict__ W,     // [1024][2048]
    const unsigned short* __restrict__ catT,  // [8192][2048]
    unsigned short* __restrict__ ftout)       // bf16 [1024][8192]
{
    __shared__ unsigned short Alds[3][BM * BK];   // 3 x 16KB
    __shared__ unsigned short Blds[3][BN * BK];   // 3 x 32KB  (total 144KB)

    const int tid = threadIdx.x;
    const int wave = tid >> 6, lane = tid & 63;

    // XCD-chunked swizzle: xcd = bid&7 gets n_idx in [xcd*4, xcd*4+4), all 8 m.
    const int bid = blockIdx.x;
    const int xcd = bid & 7;
    const int kk = bid >> 3;              // 0..31
    const int m_idx = kk >> 2;            // 0..7
    const int n_idx = xcd * 4 + (kk & 3); // 0..31
    const int m0 = m_idx * BM, n0 = n_idx * BN;
    const int wm = wave >> 2, wn = wave & 3;   // 2 x 4 wave grid

    f32x4 acc[4][4];
    for (int i = 0; i < 4; ++i)
        for (int j = 0; j < 4; ++j)
            acc[i][j] = (f32x4){0.f, 0.f, 0.f, 0.f};

    const int srow = tid >> 3;           // 0..63  (row&7 == lane>>3)
    // pre-swizzled global source column (elements): 8*((lane&7) ^ (lane>>3))
    const int scol = (((tid & 7) ^ ((tid >> 3) & 7)) * 8);
    const int fr = lane & 15;
    const int kg = lane >> 4;
    const int rswz = (fr & 7) * 8;       // read-side XOR (elements)

#define STAGE(S, T) do {                                                        \
    const int k0_ = m0 + (T) * BK;                                              \
    _Pragma("unroll")                                                           \
    for (int p = 0; p < 2; ++p) {                                               \
        const int row = p * 64 + srow;                                          \
        __builtin_amdgcn_global_load_lds(                                       \
            (as1_u32*)(const void*)(W + (size_t)(m0 + row) * KLEN + k0_ + scol),\
            (as3_u32*)(void*)(&Alds[S][row * BK + scol]), 16, 0, 0);            \
    }                                                                           \
    _Pragma("unroll")                                                           \
    for (int p = 0; p < 4; ++p) {                                               \
        const int row = p * 64 + srow;                                          \
        __builtin_amdgcn_global_load_lds(                                       \
            (as1_u32*)(const void*)(catT + (size_t)(n0 + row) * KLEN + k0_ + scol),\
            (as3_u32*)(void*)(&Blds[S][row * BK + scol]), 16, 0, 0);            \
    }                                                                           \
} while (0)

    STAGE(0, 0);
    STAGE(1, 1);

    for (int t = 0; t < NT; ++t) {
        // retire batch t (6 oldest loads); keep batch t+1 in flight
        if (t == NT - 1)
            asm volatile("s_waitcnt vmcnt(0)\ns_barrier" ::: "memory");
        else
            asm volatile("s_waitcnt vmcnt(6)\ns_barrier" ::: "memory");

        if (t + 2 < NT) {
            const int s = (t + 2) % 3;
            STAGE(s, t + 2);
        }

        const unsigned short* Ab = Alds[t % 3];
        const unsigned short* Bb = Blds[t % 3];
        bf16x8 a[2][4], b[2][4];
#pragma unroll
        for (int ks = 0; ks < 2; ++ks) {
#pragma unroll
            for (int f = 0; f < 4; ++f)
                a[ks][f] = *reinterpret_cast<const bf16x8*>(
                    Ab + (wm * 64 + f * 16 + fr) * BK + ((ks * 32 + kg * 8) ^ rswz));
#pragma unroll
            for (int f = 0; f < 4; ++f)
                b[ks][f] = *reinterpret_cast<const bf16x8*>(
                    Bb + (wn * 64 + f * 16 + fr) * BK + ((ks * 32 + kg * 8) ^ rswz));
        }
        __builtin_amdgcn_s_setprio(1);
#pragma unroll
        for (int ks = 0; ks < 2; ++ks)
#pragma unroll
            for (int fm = 0; fm < 4; ++fm)
#pragma unroll
                for (int fn = 0; fn < 4; ++fn)
                    acc[fm][fn] = __builtin_amdgcn_mfma_f32_16x16x32_bf16(
                        a[ks][fm], b[ks][fn], acc[fm][fn], 0, 0, 0);
        __builtin_amdgcn_s_setprio(0);
    }
#undef STAGE

    // epilogue: ft = bf16(acc); C/D: col=lane&15, row=(lane>>4)*4+j
    const int col16 = lane & 15, rquad = lane >> 4;
#pragma unroll
    for (int fm = 0; fm < 4; ++fm)
#pragma unroll
        for (int fn = 0; fn < 4; ++fn)
#pragma unroll
            for (int j = 0; j < 4; ++j) {
                const int m = m0 + wm * 64 + fm * 16 + rquad * 4 + j;
                const int n = n0 + wn * 64 + fn * 16 + col16;
                ftout[(size_t)m * NCOLS + n] = f2bf(acc[fm][fn][j]);
            }
}

// ---------------------------------------------------------------------------
// Kernel 4: out = LayerNorm(dec + ft/sqrt(2048)) over d=1024 per (m,b) row.
// ft bf16, dec f32, out f32.  8192 blocks x 256 threads, 4 elems/thread.
// ---------------------------------------------------------------------------
__global__ __launch_bounds__(256) void layernorm_rows(
    const unsigned short* __restrict__ ft, const float* __restrict__ dec,
    const float* __restrict__ gamma, const float* __restrict__ beta,
    float* __restrict__ out)
{
    __shared__ float ps[4], pq[4];
    const int row = blockIdx.x;
    const int tid = threadIdx.x;
    const float inv = 0.022097086912079612f;  // 1/sqrt(2048)
    const size_t base = (size_t)row * DMODEL + tid * 4;
    ushort4 u = *reinterpret_cast<const ushort4*>(ft + base);
    float4 dv = *reinterpret_cast<const float4*>(dec + base);
    float vx = dv.x + bf2f(u.x) * inv;
    float vy = dv.y + bf2f(u.y) * inv;
    float vz = dv.z + bf2f(u.z) * inv;
    float vw = dv.w + bf2f(u.w) * inv;
    float s  = vx + vy + vz + vw;
    float sq = vx * vx + vy * vy + vz * vz + vw * vw;
    for (int off = 32; off > 0; off >>= 1) {
        s  += __shfl_down(s, off);
        sq += __shfl_down(sq, off);
    }
    const int wave = tid >> 6, lane = tid & 63;
    if (lane == 0) { ps[wave] = s; pq[wave] = sq; }
    __syncthreads();
    if (tid == 0) {
        float ts = ps[0] + ps[1] + ps[2] + ps[3];
        float tq = pq[0] + pq[1] + pq[2] + pq[3];
        float mu = ts * (1.0f / DMODEL);
        float var = tq * (1.0f / DMODEL) - mu * mu;
        ps[0] = mu;
        pq[0] = rsqrtf(var + 1e-5f);
    }
    __syncthreads();
    const float mu = ps[0], rs = pq[0];
    float4 g  = *reinterpret_cast<const float4*>(gamma + tid * 4);
    float4 be = *reinterpret_cast<const float4*>(beta + tid * 4);
    float4 o;
    o.x = g.x * (vx - mu) * rs + be.x;
    o.y = g.y * (vy - mu) * rs + be.y;
    o.z = g.z * (vz - mu) * rs + be.z;
    o.w = g.w * (vw - mu) * rs + be.w;
    *reinterpret_cast<float4*>(out + base) = o;
}

extern "C" void kernel_launch(void* const* d_in, const int* in_sizes, int n_in,
                              void* d_out, int out_size, void* d_ws, size_t ws_size,
                              hipStream_t stream)
{
    const float* dec   = (const float*)d_in[0];
    const float* pos   = (const float*)d_in[1];
    const float* mems  = (const float*)d_in[2];
    const float* gamma = (const float*)d_in[3];
    const float* beta  = (const float*)d_in[4];
    const int*   addp  = (const int*)d_in[5];
    float* out = (float*)d_out;

    // ws: catT bf16 [8192][2048] (32MB) | W bf16 [1024][2048] (4MB) | ft bf16 (16MB)
    unsigned short* catT = (unsigned short*)d_ws;
    unsigned short* Wmat = catT + (size_t)NCOLS * KLEN;
    unsigned short* ft   = Wmat + (size_t)QLEN * KLEN;

    prep_transpose<<<dim3(32, 16, 8), 256, 0, stream>>>(dec, pos, mems, addp, catT);
    fill_w<<<2048, 256, 0, stream>>>(Wmat);
    gemm_band3<<<256, 512, 0, stream>>>(Wmat, catT, ft);
    layernorm_rows<<<8192, 256, 0, stream>>>(ft, dec, gamma, beta, out);
}

// Round 4
// 64.734 us; speedup vs baseline: 1.1809x; 1.0766x over previous
//
#include <hip/hip_runtime.h>
#include <hip/hip_bf16.h>

#define QLEN   1024
#define MLEN   1024
#define KLEN   2048
#define BATCH  8
#define DMODEL 1024
#define NCOLS  (BATCH * DMODEL)   // 8192
#define FTLEN  1025

#define BM 128
#define BN 256
#define BK 64
#define NT 18   // band: K in [m0, m0+1152), 18 tiles of 64

typedef __attribute__((ext_vector_type(4))) float f32x4;
typedef __attribute__((ext_vector_type(8))) short bf16x8;

typedef __attribute__((address_space(1))) const unsigned int as1_u32;
typedef __attribute__((address_space(3))) unsigned int as3_u32;

static __device__ __forceinline__ unsigned short f2bf(float f) {
    unsigned int u = __builtin_bit_cast(unsigned int, f);
    return (unsigned short)((u + 0x7fffu + ((u >> 16) & 1u)) >> 16);
}
static __device__ __forceinline__ float bf2f(unsigned short s) {
    return __builtin_bit_cast(float, (unsigned int)s << 16);
}

// ---------------------------------------------------------------------------
// Kernel 1: cat = concat(mems, dec) (+ pos_emb), cast bf16, store TRANSPOSED:
// catT[n][k], n = b*1024 + d (8192 rows), k = l (2048 cols, contiguous).
// ---------------------------------------------------------------------------
__global__ __launch_bounds__(256) void prep_transpose(
    const float* __restrict__ dec, const float* __restrict__ pos,
    const float* __restrict__ mems, const int* __restrict__ addp,
    unsigned short* __restrict__ catT)
{
    __shared__ unsigned short T[64][72];
    const int lt = blockIdx.x, dt = blockIdx.y, b = blockIdx.z;
    const int tid = threadIdx.x;
    const int add_position = addp[0];
    const int l0 = lt * 64, d0 = dt * 64;

    const int lrow = tid >> 4;         // 0..15
    const int dcol = (tid & 15) * 4;   // 0..60
    for (int p = 0; p < 4; ++p) {
        const int ll = p * 16 + lrow;
        const int l = l0 + ll;
        const int d = d0 + dcol;
        const float* src = (l < MLEN)
            ? (mems + (size_t)l * NCOLS + b * DMODEL + d)
            : (dec + (size_t)(l - MLEN) * NCOLS + b * DMODEL + d);
        float4 v = *reinterpret_cast<const float4*>(src);
        if (add_position) {
            float4 pv = *reinterpret_cast<const float4*>(pos + (size_t)l * DMODEL + d);
            v.x += pv.x; v.y += pv.y; v.z += pv.z; v.w += pv.w;
        }
        T[dcol + 0][ll] = f2bf(v.x);
        T[dcol + 1][ll] = f2bf(v.y);
        T[dcol + 2][ll] = f2bf(v.z);
        T[dcol + 3][ll] = f2bf(v.w);
    }
    __syncthreads();
    for (int p = 0; p < 2; ++p) {
        const int idx = p * 256 + tid;
        const int r = idx >> 3;
        const int c = (idx & 7) * 8;
        int4 v = *reinterpret_cast<const int4*>(&T[r][c]);
        size_t n = (size_t)(b * DMODEL + d0 + r);
        *reinterpret_cast<int4*>(&catT[n * KLEN + l0 + c]) = v;
    }
}

// ---------------------------------------------------------------------------
// Kernel 2: W[m][k] bf16, W[m][m+t] = cos(2*pi*(m*t mod 1025)/1025)/sqrt(1025)
// v_cos_f32 takes revolutions: x = r/1025 in [0,1) directly.
// ---------------------------------------------------------------------------
__global__ __launch_bounds__(256) void fill_w(unsigned short* __restrict__ W)
{
    const int idx = blockIdx.x * 256 + threadIdx.x;
    const int m = idx >> 9;
    const int k4 = (idx & 511) * 4;
    union { unsigned short s[4]; int2 v; } u;
    for (int j = 0; j < 4; ++j) {
        const int k = k4 + j;
        const int t = k - m;
        float w = 0.0f;
        if (t >= 0 && t < FTLEN) {
            const int r = (m * t) % FTLEN;
            const float x = (float)r * (1.0f / (float)FTLEN);  // revolutions
            float c;
            asm("v_cos_f32 %0, %1" : "=v"(c) : "v"(x));
            w = c * 0.03123475237772121f;   // 1/sqrt(1025)
        }
        u.s[j] = f2bf(w);
    }
    *reinterpret_cast<int2*>(&W[(size_t)m * KLEN + k4]) = u.v;
}

// ---------------------------------------------------------------------------
// Kernel 3: banded GEMM, BM=128 x BN=256, 8 waves, triple-buffered LDS,
// counted-vmcnt pipeline (2 K-tiles in flight), T2 both-sides XOR swizzle,
// 2-phase-per-K-tile interleave (m201 discipline):
//   phase = { 8 ds_read || 3 global_load_lds -> barrier -> lgkmcnt(0)
//             -> setprio(1) 16 MFMA setprio(0) -> barrier }
// Output: ft[m][n] bf16 (dec-add fused into LN).
// ---------------------------------------------------------------------------
__global__ __launch_bounds__(512) void gemm_band4(
    const unsigned short* __restrict__ W,     // [1024][2048]
    const unsigned short* __restrict__ catT,  // [8192][2048]
    unsigned short* __restrict__ ftout)       // bf16 [1024][8192]
{
    __shared__ unsigned short Alds[3][BM * BK];   // 3 x 16KB
    __shared__ unsigned short Blds[3][BN * BK];   // 3 x 32KB  (total 144KB)

    const int tid = threadIdx.x;
    const int wave = tid >> 6, lane = tid & 63;

    // XCD-chunked swizzle: xcd = bid&7 gets n_idx in [xcd*4, xcd*4+4), all 8 m.
    const int bid = blockIdx.x;
    const int xcd = bid & 7;
    const int kk = bid >> 3;              // 0..31
    const int m_idx = kk >> 2;            // 0..7
    const int n_idx = xcd * 4 + (kk & 3); // 0..31
    const int m0 = m_idx * BM, n0 = n_idx * BN;
    const int wm = wave >> 2, wn = wave & 3;   // 2 x 4 wave grid

    f32x4 acc[4][4];
    for (int i = 0; i < 4; ++i)
        for (int j = 0; j < 4; ++j)
            acc[i][j] = (f32x4){0.f, 0.f, 0.f, 0.f};

    const int srow = tid >> 3;           // 0..63  (row&7 == (tid>>3)&7)
    // pre-swizzled global source column (elements): 8*((lane&7) ^ (row&7))
    const int scol = (((tid & 7) ^ ((tid >> 3) & 7)) * 8);
    const int fr = lane & 15;
    const int kg = lane >> 4;
    const int rswz = (fr & 7) * 8;       // read-side XOR (elements)

    // STAGE halves: 6 loads/wave/tile total, 3 issued per phase.
#define STAGE_LOAD_A(S, T, P) do {                                              \
    const int k0_ = m0 + (T) * BK;                                              \
    const int row = (P) * 64 + srow;                                            \
    __builtin_amdgcn_global_load_lds(                                           \
        (as1_u32*)(const void*)(W + (size_t)(m0 + row) * KLEN + k0_ + scol),    \
        (as3_u32*)(void*)(&Alds[S][row * BK + scol]), 16, 0, 0);                \
} while (0)
#define STAGE_LOAD_B(S, T, P) do {                                              \
    const int k0_ = m0 + (T) * BK;                                              \
    const int row = (P) * 64 + srow;                                            \
    __builtin_amdgcn_global_load_lds(                                           \
        (as1_u32*)(const void*)(catT + (size_t)(n0 + row) * KLEN + k0_ + scol), \
        (as3_u32*)(void*)(&Blds[S][row * BK + scol]), 16, 0, 0);                \
} while (0)
#define STAGE_ALL(S, T) do {                                                    \
    STAGE_LOAD_A(S, T, 0); STAGE_LOAD_A(S, T, 1);                               \
    STAGE_LOAD_B(S, T, 0); STAGE_LOAD_B(S, T, 1);                               \
    STAGE_LOAD_B(S, T, 2); STAGE_LOAD_B(S, T, 3);                               \
} while (0)

    STAGE_ALL(0, 0);
    STAGE_ALL(1, 1);

    for (int t = 0; t < NT; ++t) {
        // retire tile t's 6 loads; keep tile t+1's in flight
        if (t == NT - 1)
            asm volatile("s_waitcnt vmcnt(0)" ::: "memory");
        else
            asm volatile("s_waitcnt vmcnt(6)" ::: "memory");
        __builtin_amdgcn_s_barrier();

        const unsigned short* Ab = Alds[t % 3];
        const unsigned short* Bb = Blds[t % 3];
        const int s2 = (t + 2) % 3;
        const bool pf = (t + 2 < NT);

        // ---------------- phase 0 (ks = 0) ----------------
        {
            bf16x8 a[4], b[4];
#pragma unroll
            for (int f = 0; f < 4; ++f)
                a[f] = *reinterpret_cast<const bf16x8*>(
                    Ab + (wm * 64 + f * 16 + fr) * BK + ((kg * 8) ^ rswz));
#pragma unroll
            for (int f = 0; f < 4; ++f)
                b[f] = *reinterpret_cast<const bf16x8*>(
                    Bb + (wn * 64 + f * 16 + fr) * BK + ((kg * 8) ^ rswz));
            if (pf) { STAGE_LOAD_A(s2, t + 2, 0); STAGE_LOAD_B(s2, t + 2, 0); STAGE_LOAD_B(s2, t + 2, 1); }
            __builtin_amdgcn_s_barrier();
            asm volatile("s_waitcnt lgkmcnt(0)" ::: "memory");
            __builtin_amdgcn_s_setprio(1);
#pragma unroll
            for (int fm = 0; fm < 4; ++fm)
#pragma unroll
                for (int fn = 0; fn < 4; ++fn)
                    acc[fm][fn] = __builtin_amdgcn_mfma_f32_16x16x32_bf16(
                        a[fm], b[fn], acc[fm][fn], 0, 0, 0);
            __builtin_amdgcn_s_setprio(0);
            __builtin_amdgcn_s_barrier();
        }
        // ---------------- phase 1 (ks = 1) ----------------
        {
            bf16x8 a[4], b[4];
#pragma unroll
            for (int f = 0; f < 4; ++f)
                a[f] = *reinterpret_cast<const bf16x8*>(
                    Ab + (wm * 64 + f * 16 + fr) * BK + ((32 + kg * 8) ^ rswz));
#pragma unroll
            for (int f = 0; f < 4; ++f)
                b[f] = *reinterpret_cast<const bf16x8*>(
                    Bb + (wn * 64 + f * 16 + fr) * BK + ((32 + kg * 8) ^ rswz));
            if (pf) { STAGE_LOAD_A(s2, t + 2, 1); STAGE_LOAD_B(s2, t + 2, 2); STAGE_LOAD_B(s2, t + 2, 3); }
            __builtin_amdgcn_s_barrier();
            asm volatile("s_waitcnt lgkmcnt(0)" ::: "memory");
            __builtin_amdgcn_s_setprio(1);
#pragma unroll
            for (int fm = 0; fm < 4; ++fm)
#pragma unroll
                for (int fn = 0; fn < 4; ++fn)
                    acc[fm][fn] = __builtin_amdgcn_mfma_f32_16x16x32_bf16(
                        a[fm], b[fn], acc[fm][fn], 0, 0, 0);
            __builtin_amdgcn_s_setprio(0);
            // phase-1 end barrier merged with loop-top barrier
        }
    }
#undef STAGE_ALL
#undef STAGE_LOAD_A
#undef STAGE_LOAD_B

    // epilogue: ft = bf16(acc); C/D: col=lane&15, row=(lane>>4)*4+j
    const int col16 = lane & 15, rquad = lane >> 4;
#pragma unroll
    for (int fm = 0; fm < 4; ++fm)
#pragma unroll
        for (int fn = 0; fn < 4; ++fn)
#pragma unroll
            for (int j = 0; j < 4; ++j) {
                const int m = m0 + wm * 64 + fm * 16 + rquad * 4 + j;
                const int n = n0 + wn * 64 + fn * 16 + col16;
                ftout[(size_t)m * NCOLS + n] = f2bf(acc[fm][fn][j]);
            }
}

// ---------------------------------------------------------------------------
// Kernel 4: out = LayerNorm(dec + ft/sqrt(2048)) over d=1024 per (m,b) row.
// ft bf16, dec f32, out f32.  8192 blocks x 256 threads, 4 elems/thread.
// ---------------------------------------------------------------------------
__global__ __launch_bounds__(256) void layernorm_rows(
    const unsigned short* __restrict__ ft, const float* __restrict__ dec,
    const float* __restrict__ gamma, const float* __restrict__ beta,
    float* __restrict__ out)
{
    __shared__ float ps[4], pq[4];
    const int row = blockIdx.x;
    const int tid = threadIdx.x;
    const float inv = 0.022097086912079612f;  // 1/sqrt(2048)
    const size_t base = (size_t)row * DMODEL + tid * 4;
    ushort4 u = *reinterpret_cast<const ushort4*>(ft + base);
    float4 dv = *reinterpret_cast<const float4*>(dec + base);
    float vx = dv.x + bf2f(u.x) * inv;
    float vy = dv.y + bf2f(u.y) * inv;
    float vz = dv.z + bf2f(u.z) * inv;
    float vw = dv.w + bf2f(u.w) * inv;
    float s  = vx + vy + vz + vw;
    float sq = vx * vx + vy * vy + vz * vz + vw * vw;
    for (int off = 32; off > 0; off >>= 1) {
        s  += __shfl_down(s, off);
        sq += __shfl_down(sq, off);
    }
    const int wave = tid >> 6, lane = tid & 63;
    if (lane == 0) { ps[wave] = s; pq[wave] = sq; }
    __syncthreads();
    if (tid == 0) {
        float ts = ps[0] + ps[1] + ps[2] + ps[3];
        float tq = pq[0] + pq[1] + pq[2] + pq[3];
        float mu = ts * (1.0f / DMODEL);
        float var = tq * (1.0f / DMODEL) - mu * mu;
        ps[0] = mu;
        pq[0] = rsqrtf(var + 1e-5f);
    }
    __syncthreads();
    const float mu = ps[0], rs = pq[0];
    float4 g  = *reinterpret_cast<const float4*>(gamma + tid * 4);
    float4 be = *reinterpret_cast<const float4*>(beta + tid * 4);
    float4 o;
    o.x = g.x * (vx - mu) * rs + be.x;
    o.y = g.y * (vy - mu) * rs + be.y;
    o.z = g.z * (vz - mu) * rs + be.z;
    o.w = g.w * (vw - mu) * rs + be.w;
    *reinterpret_cast<float4*>(out + base) = o;
}

extern "C" void kernel_launch(void* const* d_in, const int* in_sizes, int n_in,
                              void* d_out, int out_size, void* d_ws, size_t ws_size,
                              hipStream_t stream)
{
    const float* dec   = (const float*)d_in[0];
    const float* pos   = (const float*)d_in[1];
    const float* mems  = (const float*)d_in[2];
    const float* gamma = (const float*)d_in[3];
    const float* beta  = (const float*)d_in[4];
    const int*   addp  = (const int*)d_in[5];
    float* out = (float*)d_out;

    // ws: catT bf16 [8192][2048] (32MB) | W bf16 [1024][2048] (4MB) | ft bf16 (16MB)
    unsigned short* catT = (unsigned short*)d_ws;
    unsigned short* Wmat = catT + (size_t)NCOLS * KLEN;
    unsigned short* ft   = Wmat + (size_t)QLEN * KLEN;

    prep_transpose<<<dim3(32, 16, 8), 256, 0, stream>>>(dec, pos, mems, addp, catT);
    fill_w<<<2048, 256, 0, stream>>>(Wmat);
    gemm_band4<<<256, 512, 0, stream>>>(Wmat, catT, ft);
    layernorm_rows<<<8192, 256, 0, stream>>>(ft, dec, gamma, beta, out);
}

// Round 5
// 64.132 us; speedup vs baseline: 1.1920x; 1.0094x over previous
//
#include <hip/hip_runtime.h>
#include <hip/hip_bf16.h>

#define QLEN   1024
#define MLEN   1024
#define KLEN   2048
#define BATCH  8
#define DMODEL 1024
#define NCOLS  (BATCH * DMODEL)   // 8192
#define FTLEN  1025

#define BM 128
#define BN 256
#define BK 64
#define NT 18   // band: K in [m0, m0+1152), 18 tiles of 64

typedef __attribute__((ext_vector_type(4))) float f32x4;
typedef __attribute__((ext_vector_type(8))) short bf16x8;

typedef __attribute__((address_space(1))) const unsigned int as1_u32;
typedef __attribute__((address_space(3))) unsigned int as3_u32;

static __device__ __forceinline__ unsigned short f2bf(float f) {
    unsigned int u = __builtin_bit_cast(unsigned int, f);
    return (unsigned short)((u + 0x7fffu + ((u >> 16) & 1u)) >> 16);
}
static __device__ __forceinline__ float bf2f(unsigned short s) {
    return __builtin_bit_cast(float, (unsigned int)s << 16);
}
static __device__ __forceinline__ unsigned int packbf(float lo, float hi) {
    return (unsigned int)f2bf(lo) | ((unsigned int)f2bf(hi) << 16);
}

// ---------------------------------------------------------------------------
// Kernel 1 (v2): cat = concat(mems, dec) (+ pos_emb), cast bf16, store
// TRANSPOSED catT[n][k] (n = b*1024+d, k = l contiguous).
// Pair-packed u32 LDS transpose: T2[lp][d] = {bf16(l=2lp), bf16(2lp+1)}.
//  - Phase A: 4 batched float4 loads (+4 pos), 2 x ds_write_b128 (conflict-free).
//  - Phase B: 8 x ds_read_b32 (2-way, free) -> 2 x 16B stores (64B/4-lane groups).
// ---------------------------------------------------------------------------
__global__ __launch_bounds__(256) void prep_transpose2(
    const float* __restrict__ dec, const float* __restrict__ pos,
    const float* __restrict__ mems, const int* __restrict__ addp,
    unsigned short* __restrict__ catT)
{
    __shared__ unsigned int T2[32 * 68];   // 8704 B, stride 68 u32
    const int tid = threadIdx.x;
    const int lt = blockIdx.x, dt = blockIdx.y, b = blockIdx.z;
    const int l0 = lt * 64, d0 = dt * 64;
    const int add_position = addp[0];

    const int dloc  = (tid & 15) * 4;   // 0..60
    const int lhalf = tid >> 4;         // 0..15

    // ---- phase A: batched loads ----
    float4 vc[2][2];
#pragma unroll
    for (int p = 0; p < 2; ++p)
#pragma unroll
        for (int jl = 0; jl < 2; ++jl) {
            const int l = l0 + p * 32 + lhalf * 2 + jl;
            const float* src = (l < MLEN)
                ? (mems + (size_t)l * NCOLS + b * DMODEL + d0 + dloc)
                : (dec + (size_t)(l - MLEN) * NCOLS + b * DMODEL + d0 + dloc);
            vc[p][jl] = *reinterpret_cast<const float4*>(src);
        }
    if (add_position) {
#pragma unroll
        for (int p = 0; p < 2; ++p)
#pragma unroll
            for (int jl = 0; jl < 2; ++jl) {
                const int l = l0 + p * 32 + lhalf * 2 + jl;
                float4 pv = *reinterpret_cast<const float4*>(
                    pos + (size_t)l * DMODEL + d0 + dloc);
                vc[p][jl].x += pv.x; vc[p][jl].y += pv.y;
                vc[p][jl].z += pv.z; vc[p][jl].w += pv.w;
            }
    }
    // ---- pack & LDS store (b128) ----
#pragma unroll
    for (int p = 0; p < 2; ++p) {
        const int lp = p * 16 + lhalf;   // 0..31
        uint4 w;
        w.x = packbf(vc[p][0].x, vc[p][1].x);
        w.y = packbf(vc[p][0].y, vc[p][1].y);
        w.z = packbf(vc[p][0].z, vc[p][1].z);
        w.w = packbf(vc[p][0].w, vc[p][1].w);
        *reinterpret_cast<uint4*>(&T2[lp * 68 + dloc]) = w;
    }
    __syncthreads();
    // ---- phase B: gather columns, write catT ----
    const int d = tid >> 2;              // 0..63
    const size_t n = (size_t)b * DMODEL + d0 + d;
#pragma unroll
    for (int q = 0; q < 2; ++q) {
        const int c8 = (tid & 3) + 4 * q;    // 0..7  (8 l-elems per chunk)
        uint4 o;
        o.x = T2[(c8 * 4 + 0) * 68 + d];
        o.y = T2[(c8 * 4 + 1) * 68 + d];
        o.z = T2[(c8 * 4 + 2) * 68 + d];
        o.w = T2[(c8 * 4 + 3) * 68 + d];
        *reinterpret_cast<uint4*>(&catT[n * KLEN + l0 + c8 * 8]) = o;
    }
}

// ---------------------------------------------------------------------------
// Kernel 2: W[m][k] bf16, W[m][m+t] = cos(2*pi*(m*t mod 1025)/1025)/sqrt(1025)
// v_cos_f32 takes revolutions: x = r/1025 in [0,1) directly.
// ---------------------------------------------------------------------------
__global__ __launch_bounds__(256) void fill_w(unsigned short* __restrict__ W)
{
    const int idx = blockIdx.x * 256 + threadIdx.x;
    const int m = idx >> 9;
    const int k4 = (idx & 511) * 4;
    union { unsigned short s[4]; int2 v; } u;
    for (int j = 0; j < 4; ++j) {
        const int k = k4 + j;
        const int t = k - m;
        float w = 0.0f;
        if (t >= 0 && t < FTLEN) {
            const int r = (m * t) % FTLEN;
            const float x = (float)r * (1.0f / (float)FTLEN);  // revolutions
            float c;
            asm("v_cos_f32 %0, %1" : "=v"(c) : "v"(x));
            w = c * 0.03123475237772121f;   // 1/sqrt(1025)
        }
        u.s[j] = f2bf(w);
    }
    *reinterpret_cast<int2*>(&W[(size_t)m * KLEN + k4]) = u.v;
}

// ---------------------------------------------------------------------------
// Kernel 3: banded GEMM, BM=128 x BN=256, 8 waves, triple-buffered LDS,
// counted-vmcnt pipeline (2 K-tiles in flight), T2 both-sides XOR swizzle,
// 2-phase-per-K-tile interleave. Output ft[m][n] bf16.
// ---------------------------------------------------------------------------
__global__ __launch_bounds__(512) void gemm_band4(
    const unsigned short* __restrict__ W,     // [1024][2048]
    const unsigned short* __restrict__ catT,  // [8192][2048]
    unsigned short* __restrict__ ftout)       // bf16 [1024][8192]
{
    __shared__ unsigned short Alds[3][BM * BK];   // 3 x 16KB
    __shared__ unsigned short Blds[3][BN * BK];   // 3 x 32KB  (total 144KB)

    const int tid = threadIdx.x;
    const int wave = tid >> 6, lane = tid & 63;

    const int bid = blockIdx.x;
    const int xcd = bid & 7;
    const int kk = bid >> 3;              // 0..31
    const int m_idx = kk >> 2;            // 0..7
    const int n_idx = xcd * 4 + (kk & 3); // 0..31
    const int m0 = m_idx * BM, n0 = n_idx * BN;
    const int wm = wave >> 2, wn = wave & 3;   // 2 x 4 wave grid

    f32x4 acc[4][4];
    for (int i = 0; i < 4; ++i)
        for (int j = 0; j < 4; ++j)
            acc[i][j] = (f32x4){0.f, 0.f, 0.f, 0.f};

    const int srow = tid >> 3;           // 0..63
    const int scol = (((tid & 7) ^ ((tid >> 3) & 7)) * 8);
    const int fr = lane & 15;
    const int kg = lane >> 4;
    const int rswz = (fr & 7) * 8;       // read-side XOR (elements)

#define STAGE_LOAD_A(S, T, P) do {                                              \
    const int k0_ = m0 + (T) * BK;                                              \
    const int row = (P) * 64 + srow;                                            \
    __builtin_amdgcn_global_load_lds(                                           \
        (as1_u32*)(const void*)(W + (size_t)(m0 + row) * KLEN + k0_ + scol),    \
        (as3_u32*)(void*)(&Alds[S][row * BK + scol]), 16, 0, 0);                \
} while (0)
#define STAGE_LOAD_B(S, T, P) do {                                              \
    const int k0_ = m0 + (T) * BK;                                              \
    const int row = (P) * 64 + srow;                                            \
    __builtin_amdgcn_global_load_lds(                                           \
        (as1_u32*)(const void*)(catT + (size_t)(n0 + row) * KLEN + k0_ + scol), \
        (as3_u32*)(void*)(&Blds[S][row * BK + scol]), 16, 0, 0);                \
} while (0)
#define STAGE_ALL(S, T) do {                                                    \
    STAGE_LOAD_A(S, T, 0); STAGE_LOAD_A(S, T, 1);                               \
    STAGE_LOAD_B(S, T, 0); STAGE_LOAD_B(S, T, 1);                               \
    STAGE_LOAD_B(S, T, 2); STAGE_LOAD_B(S, T, 3);                               \
} while (0)

    STAGE_ALL(0, 0);
    STAGE_ALL(1, 1);

    for (int t = 0; t < NT; ++t) {
        if (t == NT - 1)
            asm volatile("s_waitcnt vmcnt(0)" ::: "memory");
        else
            asm volatile("s_waitcnt vmcnt(6)" ::: "memory");
        __builtin_amdgcn_s_barrier();

        const unsigned short* Ab = Alds[t % 3];
        const unsigned short* Bb = Blds[t % 3];
        const int s2 = (t + 2) % 3;
        const bool pf = (t + 2 < NT);

        // ---------------- phase 0 (ks = 0) ----------------
        {
            bf16x8 a[4], b[4];
#pragma unroll
            for (int f = 0; f < 4; ++f)
                a[f] = *reinterpret_cast<const bf16x8*>(
                    Ab + (wm * 64 + f * 16 + fr) * BK + ((kg * 8) ^ rswz));
#pragma unroll
            for (int f = 0; f < 4; ++f)
                b[f] = *reinterpret_cast<const bf16x8*>(
                    Bb + (wn * 64 + f * 16 + fr) * BK + ((kg * 8) ^ rswz));
            if (pf) { STAGE_LOAD_A(s2, t + 2, 0); STAGE_LOAD_B(s2, t + 2, 0); STAGE_LOAD_B(s2, t + 2, 1); }
            __builtin_amdgcn_s_barrier();
            asm volatile("s_waitcnt lgkmcnt(0)" ::: "memory");
            __builtin_amdgcn_s_setprio(1);
#pragma unroll
            for (int fm = 0; fm < 4; ++fm)
#pragma unroll
                for (int fn = 0; fn < 4; ++fn)
                    acc[fm][fn] = __builtin_amdgcn_mfma_f32_16x16x32_bf16(
                        a[fm], b[fn], acc[fm][fn], 0, 0, 0);
            __builtin_amdgcn_s_setprio(0);
            __builtin_amdgcn_s_barrier();
        }
        // ---------------- phase 1 (ks = 1) ----------------
        {
            bf16x8 a[4], b[4];
#pragma unroll
            for (int f = 0; f < 4; ++f)
                a[f] = *reinterpret_cast<const bf16x8*>(
                    Ab + (wm * 64 + f * 16 + fr) * BK + ((32 + kg * 8) ^ rswz));
#pragma unroll
            for (int f = 0; f < 4; ++f)
                b[f] = *reinterpret_cast<const bf16x8*>(
                    Bb + (wn * 64 + f * 16 + fr) * BK + ((32 + kg * 8) ^ rswz));
            if (pf) { STAGE_LOAD_A(s2, t + 2, 1); STAGE_LOAD_B(s2, t + 2, 2); STAGE_LOAD_B(s2, t + 2, 3); }
            __builtin_amdgcn_s_barrier();
            asm volatile("s_waitcnt lgkmcnt(0)" ::: "memory");
            __builtin_amdgcn_s_setprio(1);
#pragma unroll
            for (int fm = 0; fm < 4; ++fm)
#pragma unroll
                for (int fn = 0; fn < 4; ++fn)
                    acc[fm][fn] = __builtin_amdgcn_mfma_f32_16x16x32_bf16(
                        a[fm], b[fn], acc[fm][fn], 0, 0, 0);
            __builtin_amdgcn_s_setprio(0);
        }
    }
#undef STAGE_ALL
#undef STAGE_LOAD_A
#undef STAGE_LOAD_B

    const int col16 = lane & 15, rquad = lane >> 4;
#pragma unroll
    for (int fm = 0; fm < 4; ++fm)
#pragma unroll
        for (int fn = 0; fn < 4; ++fn)
#pragma unroll
            for (int j = 0; j < 4; ++j) {
                const int m = m0 + wm * 64 + fm * 16 + rquad * 4 + j;
                const int n = n0 + wn * 64 + fn * 16 + col16;
                ftout[(size_t)m * NCOLS + n] = f2bf(acc[fm][fn][j]);
            }
}

// ---------------------------------------------------------------------------
// Kernel 4: out = LayerNorm(dec + ft/sqrt(2048)) over d=1024 per (m,b) row.
// ---------------------------------------------------------------------------
__global__ __launch_bounds__(256) void layernorm_rows(
    const unsigned short* __restrict__ ft, const float* __restrict__ dec,
    const float* __restrict__ gamma, const float* __restrict__ beta,
    float* __restrict__ out)
{
    __shared__ float ps[4], pq[4];
    const int row = blockIdx.x;
    const int tid = threadIdx.x;
    const float inv = 0.022097086912079612f;  // 1/sqrt(2048)
    const size_t base = (size_t)row * DMODEL + tid * 4;
    ushort4 u = *reinterpret_cast<const ushort4*>(ft + base);
    float4 dv = *reinterpret_cast<const float4*>(dec + base);
    float vx = dv.x + bf2f(u.x) * inv;
    float vy = dv.y + bf2f(u.y) * inv;
    float vz = dv.z + bf2f(u.z) * inv;
    float vw = dv.w + bf2f(u.w) * inv;
    float s  = vx + vy + vz + vw;
    float sq = vx * vx + vy * vy + vz * vz + vw * vw;
    for (int off = 32; off > 0; off >>= 1) {
        s  += __shfl_down(s, off);
        sq += __shfl_down(sq, off);
    }
    const int wave = tid >> 6, lane = tid & 63;
    if (lane == 0) { ps[wave] = s; pq[wave] = sq; }
    __syncthreads();
    if (tid == 0) {
        float ts = ps[0] + ps[1] + ps[2] + ps[3];
        float tq = pq[0] + pq[1] + pq[2] + pq[3];
        float mu = ts * (1.0f / DMODEL);
        float var = tq * (1.0f / DMODEL) - mu * mu;
        ps[0] = mu;
        pq[0] = rsqrtf(var + 1e-5f);
    }
    __syncthreads();
    const float mu = ps[0], rs = pq[0];
    float4 g  = *reinterpret_cast<const float4*>(gamma + tid * 4);
    float4 be = *reinterpret_cast<const float4*>(beta + tid * 4);
    float4 o;
    o.x = g.x * (vx - mu) * rs + be.x;
    o.y = g.y * (vy - mu) * rs + be.y;
    o.z = g.z * (vz - mu) * rs + be.z;
    o.w = g.w * (vw - mu) * rs + be.w;
    *reinterpret_cast<float4*>(out + base) = o;
}

extern "C" void kernel_launch(void* const* d_in, const int* in_sizes, int n_in,
                              void* d_out, int out_size, void* d_ws, size_t ws_size,
                              hipStream_t stream)
{
    const float* dec   = (const float*)d_in[0];
    const float* pos   = (const float*)d_in[1];
    const float* mems  = (const float*)d_in[2];
    const float* gamma = (const float*)d_in[3];
    const float* beta  = (const float*)d_in[4];
    const int*   addp  = (const int*)d_in[5];
    float* out = (float*)d_out;

    // ws: catT bf16 [8192][2048] (32MB) | W bf16 [1024][2048] (4MB) | ft bf16 (16MB)
    unsigned short* catT = (unsigned short*)d_ws;
    unsigned short* Wmat = catT + (size_t)NCOLS * KLEN;
    unsigned short* ft   = Wmat + (size_t)QLEN * KLEN;

    prep_transpose2<<<dim3(32, 16, 8), 256, 0, stream>>>(dec, pos, mems, addp, catT);
    fill_w<<<2048, 256, 0, stream>>>(Wmat);
    gemm_band4<<<256, 512, 0, stream>>>(Wmat, catT, ft);
    layernorm_rows<<<8192, 256, 0, stream>>>(ft, dec, gamma, beta, out);
}